// Round 6
// baseline (157.141 us; speedup 1.0000x reference)
//
#include <hip/hip_runtime.h>
#include <stdint.h>

// Problem constants (B, L, D, H) = (8, 256, 512, 512)
#define Bb 8
#define Ll 256
#define Dd 512
#define Hh 512
#define Nout (Ll * Bb * Ll)  // 524288 elements per output tensor

#define Kc 2.8853900817779268  // 2/ln(2):  exp2(Kc*s) = e^(2s)

// JAX threefry mode: 1 = partitionable (default since jax 0.4.30)
#define RNG_PARTITIONABLE 1

typedef __attribute__((ext_vector_type(8))) short bf16x8;   // 4 VGPRs
typedef __attribute__((ext_vector_type(4))) float f32x4;    // MFMA C/D

// ---------------------------------------------------------------------------
// Threefry2x32 with key = (0, 42)  (jax.random.key(42))
// ---------------------------------------------------------------------------
__device__ __forceinline__ uint32_t rotl32(uint32_t v, int s) {
  return (v << s) | (v >> (32 - s));
}
__device__ __forceinline__ void tf_round(uint32_t& x0, uint32_t& x1, int r) {
  x0 += x1;
  x1 = rotl32(x1, r);
  x1 ^= x0;
}
__device__ __forceinline__ uint2 threefry2x32_k042(uint32_t x0, uint32_t x1) {
  const uint32_t k0 = 0u;
  const uint32_t k1 = 42u;
  const uint32_t k2 = 0x1BD11BDAu ^ k0 ^ k1;
  x0 += k0; x1 += k1;
  tf_round(x0, x1, 13); tf_round(x0, x1, 15); tf_round(x0, x1, 26); tf_round(x0, x1, 6);
  x0 += k1; x1 += k2 + 1u;
  tf_round(x0, x1, 17); tf_round(x0, x1, 29); tf_round(x0, x1, 16); tf_round(x0, x1, 24);
  x0 += k2; x1 += k0 + 2u;
  tf_round(x0, x1, 13); tf_round(x0, x1, 15); tf_round(x0, x1, 26); tf_round(x0, x1, 6);
  x0 += k0; x1 += k1 + 3u;
  tf_round(x0, x1, 17); tf_round(x0, x1, 29); tf_round(x0, x1, 16); tf_round(x0, x1, 24);
  x0 += k1; x1 += k2 + 4u;
  tf_round(x0, x1, 13); tf_round(x0, x1, 15); tf_round(x0, x1, 26); tf_round(x0, x1, 6);
  x0 += k2; x1 += k0 + 5u;
  return make_uint2(x0, x1);
}

__device__ __forceinline__ uint32_t rng_bits(uint32_t n) {
#if RNG_PARTITIONABLE
  uint2 o = threefry2x32_k042(0u, n);
  return o.x ^ o.y;
#else
  const uint32_t half = (uint32_t)(Nout / 2);
  if (n < half) {
    uint2 o = threefry2x32_k042(n, n + half);
    return o.x;
  } else {
    uint2 o = threefry2x32_k042(n - half, n);
    return o.y;
  }
#endif
}

// ---------------------------------------------------------------------------
// bf16 helpers (round-to-nearest-even split; residuals are exact in fp32)
// ---------------------------------------------------------------------------
__device__ __forceinline__ unsigned short bf16_rne(float f) {
  uint32_t u = __float_as_uint(f);
  u = (u + 0x7fffu + ((u >> 16) & 1u)) >> 16;
  return (unsigned short)u;
}
__device__ __forceinline__ float bf16_tof(unsigned short h) {
  return __uint_as_float(((uint32_t)h) << 16);
}
__device__ __forceinline__ void split3(float a, unsigned short& h,
                                       unsigned short& m, unsigned short& l) {
  h = bf16_rne(a);
  const float r1 = a - bf16_tof(h);
  m = bf16_rne(r1);
  const float r2 = r1 - bf16_tof(m);
  l = bf16_rne(r2);
}

// ---------------------------------------------------------------------------
// Pre-pass 1: split enc (fp32 [2048][512]) into 3 bf16 planes, same layout.
// ---------------------------------------------------------------------------
__global__ __launch_bounds__(256) void split_enc(
    const float* __restrict__ enc, unsigned short* __restrict__ ah,
    unsigned short* __restrict__ am, unsigned short* __restrict__ al) {
  const int idx = (blockIdx.x * 256 + threadIdx.x) * 4;
  const float4 v = *(const float4*)(enc + idx);
  ushort4 h4, m4, l4;
  split3(v.x, h4.x, m4.x, l4.x);
  split3(v.y, h4.y, m4.y, l4.y);
  split3(v.z, h4.z, m4.z, l4.z);
  split3(v.w, h4.w, m4.w, l4.w);
  *(ushort4*)(ah + idx) = h4;
  *(ushort4*)(am + idx) = m4;
  *(ushort4*)(al + idx) = l4;
}

// ---------------------------------------------------------------------------
// Pre-pass 2: Wt[n][k] = W[k][n], split into 3 bf16 planes. 64x64 LDS tile.
// z = 0 -> W_l, z = 1 -> W_r; outputs offset by z*512*512.
// ---------------------------------------------------------------------------
__global__ __launch_bounds__(256) void split_wt(
    const float* __restrict__ Wl, const float* __restrict__ Wr,
    unsigned short* __restrict__ wh, unsigned short* __restrict__ wm,
    unsigned short* __restrict__ wl) {
  const int z = blockIdx.z;
  const float* W = z ? Wr : Wl;
  const size_t zo = (size_t)z * Hh * Dd;
  const int k0 = blockIdx.x * 64;
  const int n0 = blockIdx.y * 64;
  __shared__ float tile[64][65];

  const int t = threadIdx.x;
#pragma unroll
  for (int rep = 0; rep < 4; ++rep) {
    const int idx = t + rep * 256;
    const int r = idx >> 4;         // k within tile
    const int c = (idx & 15) * 4;   // n within tile
    const float4 v = *(const float4*)(W + (size_t)(k0 + r) * Hh + n0 + c);
    tile[r][c + 0] = v.x; tile[r][c + 1] = v.y;
    tile[r][c + 2] = v.z; tile[r][c + 3] = v.w;
  }
  __syncthreads();
#pragma unroll
  for (int rep = 0; rep < 4; ++rep) {
    const int idx = t + rep * 256;
    const int rr = idx >> 4;        // n within tile
    const int cc = (idx & 15) * 4;  // k within tile
    ushort4 h4, m4, l4;
    split3(tile[cc + 0][rr], h4.x, m4.x, l4.x);
    split3(tile[cc + 1][rr], h4.y, m4.y, l4.y);
    split3(tile[cc + 2][rr], h4.z, m4.z, l4.z);
    split3(tile[cc + 3][rr], h4.w, m4.w, l4.w);
    const size_t o = zo + (size_t)(n0 + rr) * Dd + k0 + cc;
    *(ushort4*)(wh + o) = h4;
    *(ushort4*)(wm + o) = m4;
    *(ushort4*)(wl + o) = l4;
  }
}

// ---------------------------------------------------------------------------
// Kernel 1: el/er = exp2(Kc * (enc @ W)) via bf16x3 MFMA (16x16x32).
// a = ah+am+al, b = bh+bm+bl; keep products >= 2^-16: 6 MFMAs per k-chunk.
// No LDS: A/B fragments are contiguous 16B global loads (Wt is n-major).
// Per wave: m-strip 16, n 64 (4 C-frags x 2 split-accumulators), K = 512.
// Verified layouts: A[m=lane&15][k=(lane>>4)*8+j]; C/D col=lane&15,
// row=(lane>>4)*4+reg (learn_hip m89/m91/m120).
// ---------------------------------------------------------------------------
__global__ __launch_bounds__(256) void gemm_mfma(
    const unsigned short* __restrict__ ah, const unsigned short* __restrict__ am,
    const unsigned short* __restrict__ al, const unsigned short* __restrict__ wh,
    const unsigned short* __restrict__ wm, const unsigned short* __restrict__ wl,
    float* __restrict__ el, float* __restrict__ er) {
  const int z = blockIdx.z;
  const size_t zo = (size_t)z * Hh * Dd;
  float* C = z ? er : el;

  const int lane = threadIdx.x & 63;
  const int wv = threadIdx.x >> 6;
  const int m0 = blockIdx.x * 64 + wv * 16;
  const int n0 = blockIdx.y * 64;

  const int l15 = lane & 15;
  const int kq = (lane >> 4) * 8;

  const size_t a_off = (size_t)(m0 + l15) * Dd + kq;
  size_t b_off[4];
#pragma unroll
  for (int nt = 0; nt < 4; ++nt)
    b_off[nt] = zo + (size_t)(n0 + nt * 16 + l15) * Dd + kq;

  f32x4 acc[4][2];
#pragma unroll
  for (int nt = 0; nt < 4; ++nt)
#pragma unroll
    for (int hf = 0; hf < 2; ++hf) acc[nt][hf] = (f32x4){0.f, 0.f, 0.f, 0.f};

  for (int kc = 0; kc < 16; ++kc) {
    const int k0 = kc * 32;
    const bf16x8 a_h = *(const bf16x8*)(ah + a_off + k0);
    const bf16x8 a_m = *(const bf16x8*)(am + a_off + k0);
    const bf16x8 a_l = *(const bf16x8*)(al + a_off + k0);
    const int hf = kc >> 3;
#pragma unroll
    for (int nt = 0; nt < 4; ++nt) {
      const bf16x8 b_h = *(const bf16x8*)(wh + b_off[nt] + k0);
      const bf16x8 b_m = *(const bf16x8*)(wm + b_off[nt] + k0);
      const bf16x8 b_l = *(const bf16x8*)(wl + b_off[nt] + k0);
      f32x4 A = acc[nt][hf];
      A = __builtin_amdgcn_mfma_f32_16x16x32_bf16(a_h, b_h, A, 0, 0, 0);
      A = __builtin_amdgcn_mfma_f32_16x16x32_bf16(a_h, b_m, A, 0, 0, 0);
      A = __builtin_amdgcn_mfma_f32_16x16x32_bf16(a_m, b_h, A, 0, 0, 0);
      A = __builtin_amdgcn_mfma_f32_16x16x32_bf16(a_h, b_l, A, 0, 0, 0);
      A = __builtin_amdgcn_mfma_f32_16x16x32_bf16(a_l, b_h, A, 0, 0, 0);
      A = __builtin_amdgcn_mfma_f32_16x16x32_bf16(a_m, b_m, A, 0, 0, 0);
      acc[nt][hf] = A;
    }
  }

  const int rbase = (lane >> 4) * 4;
#pragma unroll
  for (int nt = 0; nt < 4; ++nt) {
    const int n = n0 + nt * 16 + l15;
#pragma unroll
    for (int reg = 0; reg < 4; ++reg) {
      const double s = (double)acc[nt][0][reg] + (double)acc[nt][1][reg];
      const int m = m0 + rbase + reg;
      C[(size_t)m * Hh + n] = __builtin_amdgcn_exp2f((float)(Kc * s));
    }
  }
}

// ---------------------------------------------------------------------------
// group4_acc: S += num/D for 4 h-terms (e = el*er = e^2s, tanh = 1-2/(1+e);
// common denominator over the 4-group). 13 VALU + 1 v_rcp per 4 terms.
// d in [1, ~2e5]; D <= ~2e21 (fp32 safe).
// ---------------------------------------------------------------------------
__device__ __forceinline__ void group4_acc(float& S, const float4 a,
                                           const float4 bv, const float4 u) {
  const float d0 = __builtin_fmaf(a.x, bv.x, 1.0f);
  const float d1 = __builtin_fmaf(a.y, bv.y, 1.0f);
  const float d2 = __builtin_fmaf(a.z, bv.z, 1.0f);
  const float d3 = __builtin_fmaf(a.w, bv.w, 1.0f);
  const float p01 = d0 * d1;
  const float p23 = d2 * d3;
  const float D = p01 * p23;
  float n01 = u.x * d1;
  n01 = __builtin_fmaf(u.y, d0, n01);
  float n23 = u.z * d3;
  n23 = __builtin_fmaf(u.w, d2, n23);
  float num = n01 * p23;
  num = __builtin_fmaf(n23, p01, num);
  S = __builtin_fmaf(num, __builtin_amdgcn_rcpf(D), S);
}

// ---------------------------------------------------------------------------
// Kernel 2a: partial x over a 64-h slice. 64x64 output tile, 4x4 micro-tile,
// split-K=8 (grid.z = ks*8 + b -> 1024 blocks = 4/CU, 35.3 KB LDS).
// part[ks][n] = Usl - 2*S  (fp32)
// ---------------------------------------------------------------------------
__global__ __launch_bounds__(256) void biaffine_part(
    const float* __restrict__ el, const float* __restrict__ er,
    const float* __restrict__ U, float* __restrict__ part) {
  const int zz = blockIdx.z;
  const int b = zz & 7;
  const int ks = zz >> 3;  // 0..7
  const int i0 = blockIdx.y * 64;
  const int j0 = blockIdx.x * 64;
  const int h0 = ks * 64;

  __shared__ float els[64][68];
  __shared__ float ers[64][68];
  __shared__ float us[64];

  const int t = threadIdx.x;
  if (t < 16) *(float4*)&us[t * 4] = *(const float4*)(U + h0 + t * 4);

  const float* elg = el + (size_t)(b * Ll + i0) * Hh + h0;
  const float* erg = er + (size_t)(b * Ll + j0) * Hh + h0;
#pragma unroll
  for (int rep = 0; rep < 4; ++rep) {
    const int idx = t + rep * 256;  // 0..1023
    const int r = idx >> 4;         // 0..63
    const int c = (idx & 15) * 4;   // 0..60
    *(float4*)&els[r][c] = *(const float4*)(elg + (size_t)r * Hh + c);
    *(float4*)&ers[r][c] = *(const float4*)(erg + (size_t)r * Hh + c);
  }
  __syncthreads();

  float usl = 0.0f;
#pragma unroll
  for (int q = 0; q < 16; ++q) {
    const float4 u = *(const float4*)&us[q * 4];
    usl += ((u.x + u.y) + u.z) + u.w;
  }

  const int ti = t >> 4;
  const int tj = t & 15;

  float S[4][4];
#pragma unroll
  for (int r = 0; r < 4; ++r)
#pragma unroll
    for (int c = 0; c < 4; ++c) S[r][c] = 0.0f;

  for (int g = 0; g < 16; ++g) {
    const int h = g * 4;
    const float4 u = *(const float4*)&us[h];
    float4 av[4], bv[4];
#pragma unroll
    for (int c = 0; c < 4; ++c) {
      av[c] = *(const float4*)&els[ti + 16 * c][h];
      bv[c] = *(const float4*)&ers[tj + 16 * c][h];
    }
#pragma unroll
    for (int r = 0; r < 4; ++r)
#pragma unroll
      for (int c = 0; c < 4; ++c) group4_acc(S[r][c], av[r], bv[c], u);
  }

  float* pslice = part + (size_t)ks * Nout;
#pragma unroll
  for (int r = 0; r < 4; ++r) {
    const int i = i0 + ti + 16 * r;
#pragma unroll
    for (int c = 0; c < 4; ++c) {
      const int j = j0 + tj + 16 * c;
      const uint32_t n = ((uint32_t)i * Bb + (uint32_t)b) * Ll + (uint32_t)j;
      pslice[n] = __builtin_fmaf(-2.0f, S[r][c], usl);
    }
  }
}

// ---------------------------------------------------------------------------
// Kernel 2b: sum the 8 slice partials (fixed order, fp64), add bias, emit
// samples / mask_scores / entropy. 4 consecutive elements per thread.
// ---------------------------------------------------------------------------
__global__ __launch_bounds__(256) void biaffine_emit(
    const float* __restrict__ part, const float* __restrict__ biasp,
    float* __restrict__ out) {
  const uint32_t n4 = (blockIdx.x * 256u + threadIdx.x) * 4u;
  double s0 = 0.0, s1 = 0.0, s2 = 0.0, s3 = 0.0;
#pragma unroll
  for (int k = 0; k < 8; ++k) {
    const float4 v = *(const float4*)(part + (size_t)k * Nout + n4);
    s0 += (double)v.x;
    s1 += (double)v.y;
    s2 += (double)v.z;
    s3 += (double)v.w;
  }
  const float bias = biasp[0];
  const double sv[4] = {s0, s1, s2, s3};

  float4 samp4, x4, ent4;
  float* sp = &samp4.x;
  float* xp = &x4.x;
  float* ep = &ent4.x;
#pragma unroll
  for (int q = 0; q < 4; ++q) {
    const uint32_t n = n4 + q;
    const int i = (int)(n >> 11);
    const int j = (int)(n & 255u);
    float x = (float)sv[q] + bias;
    if (i == j) x -= 1e8f;  // self-mask

    const double pd = 1.0 / (1.0 + exp(-(double)x));
    const float pf = (float)pd;

    const uint32_t bits = rng_bits(n);
    const float uu = __uint_as_float((bits >> 9) | 0x3f800000u) - 1.0f;
    sp[q] = (uu < pf) ? 1.0f : 0.0f;
    xp[q] = x;

    const float ax = fabsf(x);
    const float l1p = log1pf(expf(-ax));
    const float sp_pos = fmaxf(x, 0.0f) + l1p;
    const float sp_neg = fmaxf(-x, 0.0f) + l1p;
    ep[q] = pf * sp_neg + (1.0f - pf) * sp_pos;
  }
  *(float4*)(out + n4) = samp4;
  *(float4*)(out + Nout + n4) = x4;
  *(float4*)(out + 2 * (size_t)Nout + n4) = ent4;
}

// ---------------------------------------------------------------------------
extern "C" void kernel_launch(void* const* d_in, const int* in_sizes, int n_in,
                              void* d_out, int out_size, void* d_ws,
                              size_t ws_size, hipStream_t stream) {
  const float* enc = (const float*)d_in[0];  // [B,L,D]
  const float* Wl = (const float*)d_in[1];   // [D,H]
  const float* Wr = (const float*)d_in[2];   // [D,H]
  const float* U = (const float*)d_in[3];    // [H]
  const float* lb = (const float*)d_in[4];   // [1]
  float* out = (float*)d_out;

  // workspace layout (bytes): fp32 regions first, then u16 planes
  char* w = (char*)d_ws;
  float* el = (float*)w;                      w += (size_t)Bb * Ll * Hh * 4;  // 4 MB
  float* er = (float*)w;                      w += (size_t)Bb * Ll * Hh * 4;  // 4 MB
  float* part = (float*)w;                    w += (size_t)8 * Nout * 4;      // 16 MB
  unsigned short* ah = (unsigned short*)w;    w += (size_t)Bb * Ll * Dd * 2;  // 2 MB
  unsigned short* am = (unsigned short*)w;    w += (size_t)Bb * Ll * Dd * 2;
  unsigned short* al = (unsigned short*)w;    w += (size_t)Bb * Ll * Dd * 2;
  unsigned short* wh = (unsigned short*)w;    w += (size_t)2 * Dd * Hh * 2;   // 1 MB ea
  unsigned short* wm = (unsigned short*)w;    w += (size_t)2 * Dd * Hh * 2;
  unsigned short* wl = (unsigned short*)w;    w += (size_t)2 * Dd * Hh * 2;

  split_enc<<<dim3((Bb * Ll * Dd) / 1024), 256, 0, stream>>>(enc, ah, am, al);
  split_wt<<<dim3(Dd / 64, Hh / 64, 2), 256, 0, stream>>>(Wl, Wr, wh, wm, wl);
  gemm_mfma<<<dim3((Bb * Ll) / 64, Hh / 64, 2), 256, 0, stream>>>(
      ah, am, al, wh, wm, wl, el, er);
  biaffine_part<<<dim3(Ll / 64, Ll / 64, Bb * 8), 256, 0, stream>>>(el, er, U, part);
  biaffine_emit<<<dim3(Nout / 1024), 256, 0, stream>>>(part, lb, out);
}

// Round 7
// 127.205 us; speedup vs baseline: 1.2353x; 1.2353x over previous
//
#include <hip/hip_runtime.h>
#include <stdint.h>

// Problem constants (B, L, D, H) = (8, 256, 512, 512)
#define Bb 8
#define Ll 256
#define Dd 512
#define Hh 512
#define Nout (Ll * Bb * Ll)  // 524288 elements per output tensor

#define Kc 2.8853900817779268  // 2/ln(2):  exp2(Kc*s) = e^(2s)

// JAX threefry mode: 1 = partitionable (default since jax 0.4.30)
#define RNG_PARTITIONABLE 1

typedef __attribute__((ext_vector_type(8))) short bf16x8;   // 4 VGPRs
typedef __attribute__((ext_vector_type(4))) float f32x4;    // MFMA C/D

// ---------------------------------------------------------------------------
// Threefry2x32 with key = (0, 42)  (jax.random.key(42))
// ---------------------------------------------------------------------------
__device__ __forceinline__ uint32_t rotl32(uint32_t v, int s) {
  return (v << s) | (v >> (32 - s));
}
__device__ __forceinline__ void tf_round(uint32_t& x0, uint32_t& x1, int r) {
  x0 += x1;
  x1 = rotl32(x1, r);
  x1 ^= x0;
}
__device__ __forceinline__ uint2 threefry2x32_k042(uint32_t x0, uint32_t x1) {
  const uint32_t k0 = 0u;
  const uint32_t k1 = 42u;
  const uint32_t k2 = 0x1BD11BDAu ^ k0 ^ k1;
  x0 += k0; x1 += k1;
  tf_round(x0, x1, 13); tf_round(x0, x1, 15); tf_round(x0, x1, 26); tf_round(x0, x1, 6);
  x0 += k1; x1 += k2 + 1u;
  tf_round(x0, x1, 17); tf_round(x0, x1, 29); tf_round(x0, x1, 16); tf_round(x0, x1, 24);
  x0 += k2; x1 += k0 + 2u;
  tf_round(x0, x1, 13); tf_round(x0, x1, 15); tf_round(x0, x1, 26); tf_round(x0, x1, 6);
  x0 += k0; x1 += k1 + 3u;
  tf_round(x0, x1, 17); tf_round(x0, x1, 29); tf_round(x0, x1, 16); tf_round(x0, x1, 24);
  x0 += k1; x1 += k2 + 4u;
  tf_round(x0, x1, 13); tf_round(x0, x1, 15); tf_round(x0, x1, 26); tf_round(x0, x1, 6);
  x0 += k2; x1 += k0 + 5u;
  return make_uint2(x0, x1);
}

__device__ __forceinline__ uint32_t rng_bits(uint32_t n) {
#if RNG_PARTITIONABLE
  uint2 o = threefry2x32_k042(0u, n);
  return o.x ^ o.y;
#else
  const uint32_t half = (uint32_t)(Nout / 2);
  if (n < half) {
    uint2 o = threefry2x32_k042(n, n + half);
    return o.x;
  } else {
    uint2 o = threefry2x32_k042(n - half, n);
    return o.y;
  }
#endif
}

// ---------------------------------------------------------------------------
// bf16 helpers (round-to-nearest-even split; residuals are exact in fp32)
// ---------------------------------------------------------------------------
__device__ __forceinline__ unsigned short bf16_rne(float f) {
  uint32_t u = __float_as_uint(f);
  u = (u + 0x7fffu + ((u >> 16) & 1u)) >> 16;
  return (unsigned short)u;
}
__device__ __forceinline__ float bf16_tof(unsigned short h) {
  return __uint_as_float(((uint32_t)h) << 16);
}
__device__ __forceinline__ void split3(float a, unsigned short& h,
                                       unsigned short& m, unsigned short& l) {
  h = bf16_rne(a);
  const float r1 = a - bf16_tof(h);
  m = bf16_rne(r1);
  const float r2 = r1 - bf16_tof(m);
  l = bf16_rne(r2);
}

// ---------------------------------------------------------------------------
// Pre-pass 1: split enc (fp32 [2048][512]) into 3 bf16 planes, same layout.
// ---------------------------------------------------------------------------
__global__ __launch_bounds__(256) void split_enc(
    const float* __restrict__ enc, unsigned short* __restrict__ ah,
    unsigned short* __restrict__ am, unsigned short* __restrict__ al) {
  const int idx = (blockIdx.x * 256 + threadIdx.x) * 4;
  const float4 v = *(const float4*)(enc + idx);
  ushort4 h4, m4, l4;
  split3(v.x, h4.x, m4.x, l4.x);
  split3(v.y, h4.y, m4.y, l4.y);
  split3(v.z, h4.z, m4.z, l4.z);
  split3(v.w, h4.w, m4.w, l4.w);
  *(ushort4*)(ah + idx) = h4;
  *(ushort4*)(am + idx) = m4;
  *(ushort4*)(al + idx) = l4;
}

// ---------------------------------------------------------------------------
// Pre-pass 2: Wt[n][k] = W[k][n], split into 3 bf16 planes. 64x64 LDS tile.
// z = 0 -> W_l, z = 1 -> W_r; outputs offset by z*512*512.
// ---------------------------------------------------------------------------
__global__ __launch_bounds__(256) void split_wt(
    const float* __restrict__ Wl, const float* __restrict__ Wr,
    unsigned short* __restrict__ wh, unsigned short* __restrict__ wm,
    unsigned short* __restrict__ wl) {
  const int z = blockIdx.z;
  const float* W = z ? Wr : Wl;
  const size_t zo = (size_t)z * Hh * Dd;
  const int k0 = blockIdx.x * 64;
  const int n0 = blockIdx.y * 64;
  __shared__ float tile[64][65];

  const int t = threadIdx.x;
#pragma unroll
  for (int rep = 0; rep < 4; ++rep) {
    const int idx = t + rep * 256;
    const int r = idx >> 4;         // k within tile
    const int c = (idx & 15) * 4;   // n within tile
    const float4 v = *(const float4*)(W + (size_t)(k0 + r) * Hh + n0 + c);
    tile[r][c + 0] = v.x; tile[r][c + 1] = v.y;
    tile[r][c + 2] = v.z; tile[r][c + 3] = v.w;
  }
  __syncthreads();
#pragma unroll
  for (int rep = 0; rep < 4; ++rep) {
    const int idx = t + rep * 256;
    const int rr = idx >> 4;        // n within tile
    const int cc = (idx & 15) * 4;  // k within tile
    ushort4 h4, m4, l4;
    split3(tile[cc + 0][rr], h4.x, m4.x, l4.x);
    split3(tile[cc + 1][rr], h4.y, m4.y, l4.y);
    split3(tile[cc + 2][rr], h4.z, m4.z, l4.z);
    split3(tile[cc + 3][rr], h4.w, m4.w, l4.w);
    const size_t o = zo + (size_t)(n0 + rr) * Dd + k0 + cc;
    *(ushort4*)(wh + o) = h4;
    *(ushort4*)(wm + o) = m4;
    *(ushort4*)(wl + o) = l4;
  }
}

// ---------------------------------------------------------------------------
// Kernel 1: el/er = exp2(Kc * (enc @ W)) via bf16x3 MFMA (16x16x32),
// LDS-staged with global_load_lds (async direct-to-LDS) + double buffer.
//
// Block: 64m x 64n tile, 4 waves; wave w owns the 32x32 quadrant
// (mp = w&1, np = w>>1) as 2x2 MFMA tiles. Chunk = 32k.
// LDS per buffer: A 12 x 1KB fragment-packed blocks [plane(3)][mtile(4)],
//                 B same with ntiles -> 24 KB; x2 buffers = 48 KB.
// Fragment packing: within a 1KB block, lane's 16B at lane*16 IS the MFMA
// fragment (A[m=lane&15][k=(lane>>4)*8+j]; Wt is [n][k] so B identical).
// global_load_lds dest = uniform base + lane*16 -> constraint satisfied.
// Math identical to R6 (bit-identical el/er): 6 MFMAs (hh,hm,mh,hl,lh,mm),
// accumulators split by K-half, fp64 combine, exp2(Kc*dot).
// ---------------------------------------------------------------------------
__global__ __launch_bounds__(256) void gemm_mfma(
    const unsigned short* __restrict__ ah, const unsigned short* __restrict__ am,
    const unsigned short* __restrict__ al, const unsigned short* __restrict__ wh,
    const unsigned short* __restrict__ wm, const unsigned short* __restrict__ wl,
    float* __restrict__ el, float* __restrict__ er) {
  const int z = blockIdx.z;
  const size_t zo = (size_t)z * Hh * Dd;
  float* C = z ? er : el;
  const int m0 = blockIdx.x * 64;
  const int n0 = blockIdx.y * 64;

  // [buf][12 blocks of 512 u16 = 1KB]
  __shared__ unsigned short Asm[2][12 * 512];
  __shared__ unsigned short Bsm[2][12 * 512];

  const int t = threadIdx.x;
  const int lane = t & 63;
  const int wv = t >> 6;
  const int l15 = lane & 15;
  const int kq8 = (lane >> 4) * 8;

  // staging descriptors: 6 loads per wave, q = wv*6 + s in 0..23
  const unsigned short* gp[6];
  size_t go[6];      // element offset, without k0
  int lq[6];         // LDS block index (u16 units, without buf)
  bool isA[6];
#pragma unroll
  for (int s = 0; s < 6; ++s) {
    const int q = wv * 6 + s;
    if (q < 12) {
      const int p = q >> 2, mt = q & 3;
      gp[s] = (p == 0) ? ah : (p == 1) ? am : al;
      go[s] = (size_t)(m0 + mt * 16 + l15) * Dd + kq8;
      lq[s] = q * 512;
      isA[s] = true;
    } else {
      const int q2 = q - 12;
      const int p = q2 >> 2, nt = q2 & 3;
      gp[s] = (p == 0) ? wh : (p == 1) ? wm : wl;
      go[s] = zo + (size_t)(n0 + nt * 16 + l15) * Dd + kq8;
      lq[s] = q2 * 512;
      isA[s] = false;
    }
  }

  auto stage = [&](int buf, int kc) {
    const int k0 = kc * 32;
#pragma unroll
    for (int s = 0; s < 6; ++s) {
      unsigned short* dst = isA[s] ? &Asm[buf][lq[s]] : &Bsm[buf][lq[s]];
      __builtin_amdgcn_global_load_lds(
          (const __attribute__((address_space(1))) void*)(gp[s] + go[s] + k0),
          (__attribute__((address_space(3))) void*)dst, 16, 0, 0);
    }
  };

  const int mp = wv & 1;   // m-pair: mtiles {2mp, 2mp+1}
  const int np = wv >> 1;  // n-pair: ntiles {2np, 2np+1}

  f32x4 acc[2][2][2];  // [mi][ni][hf]
#pragma unroll
  for (int mi = 0; mi < 2; ++mi)
#pragma unroll
    for (int ni = 0; ni < 2; ++ni)
#pragma unroll
      for (int hf = 0; hf < 2; ++hf) acc[mi][ni][hf] = (f32x4){0.f, 0.f, 0.f, 0.f};

  stage(0, 0);
  __syncthreads();

  for (int kc = 0; kc < 16; ++kc) {
    const int buf = kc & 1;
    if (kc < 15) stage(buf ^ 1, kc + 1);

    bf16x8 af[2][3], bfr[2][3];
#pragma unroll
    for (int mi = 0; mi < 2; ++mi)
#pragma unroll
      for (int p = 0; p < 3; ++p)
        af[mi][p] = *(const bf16x8*)&Asm[buf][(p * 4 + mp * 2 + mi) * 512 + lane * 8];
#pragma unroll
    for (int ni = 0; ni < 2; ++ni)
#pragma unroll
      for (int p = 0; p < 3; ++p)
        bfr[ni][p] = *(const bf16x8*)&Bsm[buf][(p * 4 + np * 2 + ni) * 512 + lane * 8];

    const int hf = kc >> 3;
#pragma unroll
    for (int mi = 0; mi < 2; ++mi)
#pragma unroll
      for (int ni = 0; ni < 2; ++ni) {
        f32x4 A = acc[mi][ni][hf];
        A = __builtin_amdgcn_mfma_f32_16x16x32_bf16(af[mi][0], bfr[ni][0], A, 0, 0, 0);
        A = __builtin_amdgcn_mfma_f32_16x16x32_bf16(af[mi][0], bfr[ni][1], A, 0, 0, 0);
        A = __builtin_amdgcn_mfma_f32_16x16x32_bf16(af[mi][1], bfr[ni][0], A, 0, 0, 0);
        A = __builtin_amdgcn_mfma_f32_16x16x32_bf16(af[mi][0], bfr[ni][2], A, 0, 0, 0);
        A = __builtin_amdgcn_mfma_f32_16x16x32_bf16(af[mi][2], bfr[ni][0], A, 0, 0, 0);
        A = __builtin_amdgcn_mfma_f32_16x16x32_bf16(af[mi][1], bfr[ni][1], A, 0, 0, 0);
        acc[mi][ni][hf] = A;
      }
    __syncthreads();
  }

  const int rbase = (lane >> 4) * 4;
#pragma unroll
  for (int mi = 0; mi < 2; ++mi) {
    const int mbase = m0 + (mp * 2 + mi) * 16 + rbase;
#pragma unroll
    for (int ni = 0; ni < 2; ++ni) {
      const int n = n0 + (np * 2 + ni) * 16 + l15;
#pragma unroll
      for (int reg = 0; reg < 4; ++reg) {
        const double s = (double)acc[mi][ni][0][reg] + (double)acc[mi][ni][1][reg];
        C[(size_t)(mbase + reg) * Hh + n] = __builtin_amdgcn_exp2f((float)(Kc * s));
      }
    }
  }
}

// ---------------------------------------------------------------------------
// group4_acc: S += num/D for 4 h-terms (e = el*er = e^2s, tanh = 1-2/(1+e);
// common denominator over the 4-group). 13 VALU + 1 v_rcp per 4 terms.
// d in [1, ~2e5]; D <= ~2e21 (fp32 safe).
// ---------------------------------------------------------------------------
__device__ __forceinline__ void group4_acc(float& S, const float4 a,
                                           const float4 bv, const float4 u) {
  const float d0 = __builtin_fmaf(a.x, bv.x, 1.0f);
  const float d1 = __builtin_fmaf(a.y, bv.y, 1.0f);
  const float d2 = __builtin_fmaf(a.z, bv.z, 1.0f);
  const float d3 = __builtin_fmaf(a.w, bv.w, 1.0f);
  const float p01 = d0 * d1;
  const float p23 = d2 * d3;
  const float D = p01 * p23;
  float n01 = u.x * d1;
  n01 = __builtin_fmaf(u.y, d0, n01);
  float n23 = u.z * d3;
  n23 = __builtin_fmaf(u.w, d2, n23);
  float num = n01 * p23;
  num = __builtin_fmaf(n23, p01, num);
  S = __builtin_fmaf(num, __builtin_amdgcn_rcpf(D), S);
}

// ---------------------------------------------------------------------------
// Kernel 2a: partial x over a 64-h slice. 64x64 output tile, 4x4 micro-tile,
// split-K=8 (grid.z = ks*8 + b -> 1024 blocks = 4/CU, 35.3 KB LDS).
// part[ks][n] = Usl - 2*S  (fp32)
// ---------------------------------------------------------------------------
__global__ __launch_bounds__(256) void biaffine_part(
    const float* __restrict__ el, const float* __restrict__ er,
    const float* __restrict__ U, float* __restrict__ part) {
  const int zz = blockIdx.z;
  const int b = zz & 7;
  const int ks = zz >> 3;  // 0..7
  const int i0 = blockIdx.y * 64;
  const int j0 = blockIdx.x * 64;
  const int h0 = ks * 64;

  __shared__ float els[64][68];
  __shared__ float ers[64][68];
  __shared__ float us[64];

  const int t = threadIdx.x;
  if (t < 16) *(float4*)&us[t * 4] = *(const float4*)(U + h0 + t * 4);

  const float* elg = el + (size_t)(b * Ll + i0) * Hh + h0;
  const float* erg = er + (size_t)(b * Ll + j0) * Hh + h0;
#pragma unroll
  for (int rep = 0; rep < 4; ++rep) {
    const int idx = t + rep * 256;  // 0..1023
    const int r = idx >> 4;         // 0..63
    const int c = (idx & 15) * 4;   // 0..60
    *(float4*)&els[r][c] = *(const float4*)(elg + (size_t)r * Hh + c);
    *(float4*)&ers[r][c] = *(const float4*)(erg + (size_t)r * Hh + c);
  }
  __syncthreads();

  float usl = 0.0f;
#pragma unroll
  for (int q = 0; q < 16; ++q) {
    const float4 u = *(const float4*)&us[q * 4];
    usl += ((u.x + u.y) + u.z) + u.w;
  }

  const int ti = t >> 4;
  const int tj = t & 15;

  float S[4][4];
#pragma unroll
  for (int r = 0; r < 4; ++r)
#pragma unroll
    for (int c = 0; c < 4; ++c) S[r][c] = 0.0f;

  for (int g = 0; g < 16; ++g) {
    const int h = g * 4;
    const float4 u = *(const float4*)&us[h];
    float4 av[4], bv[4];
#pragma unroll
    for (int c = 0; c < 4; ++c) {
      av[c] = *(const float4*)&els[ti + 16 * c][h];
      bv[c] = *(const float4*)&ers[tj + 16 * c][h];
    }
#pragma unroll
    for (int r = 0; r < 4; ++r)
#pragma unroll
      for (int c = 0; c < 4; ++c) group4_acc(S[r][c], av[r], bv[c], u);
  }

  float* pslice = part + (size_t)ks * Nout;
#pragma unroll
  for (int r = 0; r < 4; ++r) {
    const int i = i0 + ti + 16 * r;
#pragma unroll
    for (int c = 0; c < 4; ++c) {
      const int j = j0 + tj + 16 * c;
      const uint32_t n = ((uint32_t)i * Bb + (uint32_t)b) * Ll + (uint32_t)j;
      pslice[n] = __builtin_fmaf(-2.0f, S[r][c], usl);
    }
  }
}

// ---------------------------------------------------------------------------
// Kernel 2b: sum the 8 slice partials (fixed order, fp64), add bias, emit
// samples / mask_scores / entropy. 4 consecutive elements per thread.
// ---------------------------------------------------------------------------
__global__ __launch_bounds__(256) void biaffine_emit(
    const float* __restrict__ part, const float* __restrict__ biasp,
    float* __restrict__ out) {
  const uint32_t n4 = (blockIdx.x * 256u + threadIdx.x) * 4u;
  double s0 = 0.0, s1 = 0.0, s2 = 0.0, s3 = 0.0;
#pragma unroll
  for (int k = 0; k < 8; ++k) {
    const float4 v = *(const float4*)(part + (size_t)k * Nout + n4);
    s0 += (double)v.x;
    s1 += (double)v.y;
    s2 += (double)v.z;
    s3 += (double)v.w;
  }
  const float bias = biasp[0];
  const double sv[4] = {s0, s1, s2, s3};

  float4 samp4, x4, ent4;
  float* sp = &samp4.x;
  float* xp = &x4.x;
  float* ep = &ent4.x;
#pragma unroll
  for (int q = 0; q < 4; ++q) {
    const uint32_t n = n4 + q;
    const int i = (int)(n >> 11);
    const int j = (int)(n & 255u);
    float x = (float)sv[q] + bias;
    if (i == j) x -= 1e8f;  // self-mask

    const double pd = 1.0 / (1.0 + exp(-(double)x));
    const float pf = (float)pd;

    const uint32_t bits = rng_bits(n);
    const float uu = __uint_as_float((bits >> 9) | 0x3f800000u) - 1.0f;
    sp[q] = (uu < pf) ? 1.0f : 0.0f;
    xp[q] = x;

    const float ax = fabsf(x);
    const float l1p = log1pf(expf(-ax));
    const float sp_pos = fmaxf(x, 0.0f) + l1p;
    const float sp_neg = fmaxf(-x, 0.0f) + l1p;
    ep[q] = pf * sp_neg + (1.0f - pf) * sp_pos;
  }
  *(float4*)(out + n4) = samp4;
  *(float4*)(out + Nout + n4) = x4;
  *(float4*)(out + 2 * (size_t)Nout + n4) = ent4;
}

// ---------------------------------------------------------------------------
extern "C" void kernel_launch(void* const* d_in, const int* in_sizes, int n_in,
                              void* d_out, int out_size, void* d_ws,
                              size_t ws_size, hipStream_t stream) {
  const float* enc = (const float*)d_in[0];  // [B,L,D]
  const float* Wl = (const float*)d_in[1];   // [D,H]
  const float* Wr = (const float*)d_in[2];   // [D,H]
  const float* U = (const float*)d_in[3];    // [H]
  const float* lb = (const float*)d_in[4];   // [1]
  float* out = (float*)d_out;

  // workspace layout (bytes): fp32 regions first, then u16 planes
  char* w = (char*)d_ws;
  float* el = (float*)w;                      w += (size_t)Bb * Ll * Hh * 4;  // 4 MB
  float* er = (float*)w;                      w += (size_t)Bb * Ll * Hh * 4;  // 4 MB
  float* part = (float*)w;                    w += (size_t)8 * Nout * 4;      // 16 MB
  unsigned short* ah = (unsigned short*)w;    w += (size_t)Bb * Ll * Dd * 2;  // 2 MB
  unsigned short* am = (unsigned short*)w;    w += (size_t)Bb * Ll * Dd * 2;
  unsigned short* al = (unsigned short*)w;    w += (size_t)Bb * Ll * Dd * 2;
  unsigned short* wh = (unsigned short*)w;    w += (size_t)2 * Dd * Hh * 2;   // 1 MB ea
  unsigned short* wm = (unsigned short*)w;    w += (size_t)2 * Dd * Hh * 2;
  unsigned short* wl = (unsigned short*)w;    w += (size_t)2 * Dd * Hh * 2;

  split_enc<<<dim3((Bb * Ll * Dd) / 1024), 256, 0, stream>>>(enc, ah, am, al);
  split_wt<<<dim3(Dd / 64, Hh / 64, 2), 256, 0, stream>>>(Wl, Wr, wh, wm, wl);
  gemm_mfma<<<dim3((Bb * Ll) / 64, Hh / 64, 2), 256, 0, stream>>>(
      ah, am, al, wh, wm, wl, el, er);
  biaffine_part<<<dim3(Ll / 64, Ll / 64, Bb * 8), 256, 0, stream>>>(el, er, U, part);
  biaffine_emit<<<dim3(Nout / 1024), 256, 0, stream>>>(part, lb, out);
}